// Round 1
// baseline (27.122 us; speedup 1.0000x reference)
//
#include <hip/hip_runtime.h>
#include <math.h>

// Gaussian map generator: out[z,y,x] = sum_a amp[a] * exp(-c * |r_voxel - r_atom|^2)
// c = 1/(2 sigma^2), sigma = resolution/(sqrt(2) pi).  With resolution=2, c~=2.467,
// so contributions vanish (<1e-17) beyond ~4 A.  Scatter per atom with a hard cutoff
// R = sqrt(40/c); separable per-dim exp tables in LDS; fp32 atomicAdd into d_out.

__global__ __launch_bounds__(128)
void scatter_gauss(const float* __restrict__ coords,
                   const float* __restrict__ amps,
                   const float* __restrict__ pix,
                   const int* __restrict__ resp,
                   float* __restrict__ out)
{
    const int NXg = 128, NYg = 128, NZg = 128;
    __shared__ float ex[128], ey[128], ez[128];

    const int a = blockIdx.x;
    const float cx = coords[a * 3 + 0];
    const float cy = coords[a * 3 + 1];
    const float cz = coords[a * 3 + 2];
    const float amp = amps[a];

    // sigma = res / (sqrt(2)*pi); c = 1/(2 sigma^2)
    const float res = (float)resp[0];
    const float sigma = res / (sqrtf(2.0f) * 3.14159265358979323846f);
    const float c = 1.0f / (2.0f * sigma * sigma);
    // cutoff: exp(-c R^2) = exp(-40) ~ 4e-18 -> truncation far below threshold
    const float R = sqrtf(40.0f / c);

    // derive the affine grid from the actual pix_coords input (robust to origin/step)
    const float ox = pix[0], oy = pix[1], oz = pix[2];
    const float sx = pix[3] - pix[0];                   // x step (ix fastest)
    const float sy = pix[NXg * 3 + 1] - pix[1];         // y step
    const float sz = pix[NXg * NYg * 3 + 2] - pix[2];   // z step

    int ixlo = max(0,       (int)ceilf ((cx - R - ox) / sx));
    int ixhi = min(NXg - 1, (int)floorf((cx + R - ox) / sx));
    int iylo = max(0,       (int)ceilf ((cy - R - oy) / sy));
    int iyhi = min(NYg - 1, (int)floorf((cy + R - oy) / sy));
    int izlo = max(0,       (int)ceilf ((cz - R - oz) / sz));
    int izhi = min(NZg - 1, (int)floorf((cz + R - oz) / sz));

    const int nx = ixhi - ixlo + 1;
    const int ny = iyhi - iylo + 1;
    const int nz = izhi - izlo + 1;
    if (nx <= 0 || ny <= 0 || nz <= 0) return;  // atom outside grid (uniform branch)

    // per-dim Gaussian tables (amp folded into z table)
    for (int i = threadIdx.x; i < nx; i += blockDim.x) {
        float d = ox + (float)(ixlo + i) * sx - cx;
        ex[i] = __expf(-c * d * d);
    }
    for (int i = threadIdx.x; i < ny; i += blockDim.x) {
        float d = oy + (float)(iylo + i) * sy - cy;
        ey[i] = __expf(-c * d * d);
    }
    for (int i = threadIdx.x; i < nz; i += blockDim.x) {
        float d = oz + (float)(izlo + i) * sz - cz;
        ez[i] = amp * __expf(-c * d * d);
    }
    __syncthreads();

    const int tasks = nx * ny * nz;
    for (int t = threadIdx.x; t < tasks; t += blockDim.x) {
        int dx = t % nx;          // x fastest -> consecutive lanes, consecutive addrs
        int r  = t / nx;
        int dy = r % ny;
        int dz = r / ny;
        float g = ex[dx] * ey[dy] * ez[dz];
        int idx = ((izlo + dz) * NYg + (iylo + dy)) * NXg + (ixlo + dx);
        atomicAdd(out + idx, g);
    }
}

extern "C" void kernel_launch(void* const* d_in, const int* in_sizes, int n_in,
                              void* d_out, int out_size, void* d_ws, size_t ws_size,
                              hipStream_t stream)
{
    const float* coords = (const float*)d_in[0];   // (3000, 3) f32
    const float* amps   = (const float*)d_in[1];   // (3000,)  f32
    const float* pix    = (const float*)d_in[2];   // (2097152, 3) f32
    const int*   resp   = (const int*)d_in[3];     // scalar int
    float* out = (float*)d_out;                    // (1,128,128,128) f32

    const int n_atoms = in_sizes[1];

    // harness poisons d_out with 0xAA and does not re-poison between replays:
    // we must zero it ourselves every call.
    hipMemsetAsync(out, 0, (size_t)out_size * sizeof(float), stream);
    scatter_gauss<<<n_atoms, 128, 0, stream>>>(coords, amps, pix, resp, out);
}